// Round 1
// baseline (23968.968 us; speedup 1.0000x reference)
//
#include <hip/hip_runtime.h>
#include <math.h>

// HybridQLSTM persistent kernel v4: flag barriers replaced by tag-in-word
// data polling. T=1024, B=64, D_IN=256, H=256, 4 gates.
// 16 blocks = 4 gates x 4 col-tiles, 256 threads (4 waves), weights in LDS.
// All cross-block exchange words are u64: [63:48]=step tag, payloads below
// ([47:32], [15:0] = two f16 / two u16-fixed). Double-buffered by parity.
// Consumers poll tags with relaxed agent-scope (IC) loads -> one one-way IC
// latency per exchange instead of syncthreads+flag round-trip. No intra-loop
// __syncthreads at all; waves self-synchronize on exactly the words they need.

#define TS    1024
#define NELEM 16384

typedef unsigned long long u64;
typedef unsigned int u32;
typedef unsigned short u16;
typedef _Float16 f16;
typedef __attribute__((ext_vector_type(8))) _Float16 half8;
typedef __attribute__((ext_vector_type(4))) float f32x4;

// ---- relaxed agent-scope (IC-coherent) accessors ----
__device__ __forceinline__ u64 ld_a8(const u64* p) {
    return __hip_atomic_load(p, __ATOMIC_RELAXED, __HIP_MEMORY_SCOPE_AGENT);
}
__device__ __forceinline__ void st_a8(u64* p, u64 v) {
    __hip_atomic_store(p, v, __ATOMIC_RELAXED, __HIP_MEMORY_SCOPE_AGENT);
}

// fast tanh/sigmoid via v_exp/v_rcp (err ~1e-6, << f16 quantization)
__device__ __forceinline__ float fast_tanh(float xx) {
    float e = __expf(2.0f * xx);
    return 1.0f - 2.0f * __builtin_amdgcn_rcpf(e + 1.0f);
}
__device__ __forceinline__ float fast_sig(float xx) {
    return __builtin_amdgcn_rcpf(1.0f + __expf(-xx));
}

// ---- init: zero all exchange words (tag=0; also h(0)=0 payload) ----
// Must run every launch: stale tags from a previous replay would satisfy polls.
__global__ __launch_bounds__(256) void qinit(u64* ws64, int n) {
    int stride = gridDim.x * 256;
    for (int i = blockIdx.x * 256 + threadIdx.x; i < n; i += stride)
        st_a8(&ws64[i], 0ull);
}

// ---- persistent kernel ----
__global__ __launch_bounds__(256, 1) void qlstm_persist(
    const float* __restrict__ x,      // [TS, 64, 256] fp32
    const float* __restrict__ W1,     // [4, 512, 256]
    const float* __restrict__ b1,     // [4, 256]
    const float* __restrict__ W2,     // [4, 256, 256]
    const float* __restrict__ b2,     // [4, 256]
    float* __restrict__ out,          // stacked ++ hx ++ cx
    u64* __restrict__ h64,            // [2][64][128]   tag|h_odd|-|h_even
    u64* __restrict__ hid64,          // [2][4][64][128] tag|m_odd|-|m_even
    u64* __restrict__ gat64)          // [2][4][64][128] tag|-|q_odd|q_even
{
    const int tid = threadIdx.x;
    const int bid = blockIdx.x;
    const int g  = bid >> 2;          // gate 0..3
    const int ct = bid & 3;           // column tile 0..3 (64 cols)

    // LDS: W1 [16 kt][4 nt][64 lanes][8 f16] = 64 KB ; W2 [8 kt][4 nt][...] = 32 KB
    __shared__ f16 w1s[16 * 4 * 512];
    __shared__ f16 w2s[8 * 4 * 512];
    {
        const float* W1g = W1 + (size_t)g * 512 * 256;
        for (int i = tid; i < 16 * 4 * 64; i += 256) {
            int kt = i >> 8, nt = (i >> 6) & 3, lane = i & 63;
            int k0 = kt * 32 + (lane >> 4) * 8;
            int col = ct * 64 + nt * 16 + (lane & 15);
#pragma unroll
            for (int j = 0; j < 8; ++j)
                w1s[((kt * 4 + nt) * 64 + lane) * 8 + j] = (f16)W1g[(size_t)(k0 + j) * 256 + col];
        }
        const float* W2g = W2 + (size_t)g * 256 * 256;
        for (int i = tid; i < 8 * 4 * 64; i += 256) {
            int kt = i >> 8, nt = (i >> 6) & 3, lane = i & 63;
            int k0 = kt * 32 + (lane >> 4) * 8;
            int col = ct * 64 + nt * 16 + (lane & 15);
#pragma unroll
            for (int j = 0; j < 8; ++j)
                w2s[((kt * 4 + nt) * 64 + lane) * 8 + j] = (f16)W2g[(size_t)(k0 + j) * 256 + col];
        }
        __syncthreads();
    }

    const int l    = tid & 63;
    const int w    = tid >> 6;        // wave: owns batch rows w*16 .. w*16+15
    const int quad = l >> 4;
    const int n15  = l & 15;
    const int brow = w * 16 + n15;    // A-operand row this lane loads
    const int bo   = w * 16 + quad * 4;  // C/D row base
    float b1v[4], b2v[4];
#pragma unroll
    for (int nt = 0; nt < 4; ++nt) {
        b1v[nt] = b1[g * 256 + ct * 64 + nt * 16 + n15];
        b2v[nt] = b2[g * 256 + ct * 64 + nt * 16 + n15];
    }
    // update-phase ownership: 4 consecutive cols of one row
    const int e0   = bid * 1024 + tid * 4;       // [0, 16384)
    const int urow = e0 >> 8;
    const int ucol = e0 & 255;
    float creg[4] = {0.f, 0.f, 0.f, 0.f};

    f32x4 acc[4];
#pragma unroll
    for (int nt = 0; nt < 4; ++nt) acc[nt] = (f32x4){0.f, 0.f, 0.f, 0.f};

    // ---- stage1 x-part (kt 0..7), no h dependence; peeled for t=0 ----
    {
        const float* xr = x + (size_t)brow * 256;
#pragma unroll
        for (int kt = 0; kt < 8; ++kt) {
            float a[8];
            *(float4*)&a[0] = *(const float4*)(xr + kt * 32 + quad * 8);
            *(float4*)&a[4] = *(const float4*)(xr + kt * 32 + quad * 8 + 4);
            half8 ah;
#pragma unroll
            for (int j = 0; j < 8; ++j) ah[j] = (f16)a[j];
#pragma unroll
            for (int nt = 0; nt < 4; ++nt)
                acc[nt] = __builtin_amdgcn_mfma_f32_16x16x32_f16(
                    ah, *(const half8*)&w1s[((kt * 4 + nt) * 64 + l) * 8], acc[nt], 0, 0, 0);
        }
    }

    for (int t = 0; t < TS; ++t) {
        // ---- poll h(version t) + stage1 h-part (kt 8..15) ----
        {
            const u64* hb = h64 + (size_t)(t & 1) * 8192 + (size_t)brow * 128;
            const u16 wantH = (u16)t;
            u64 hv[32];
            for (;;) {
                bool ok = true;
#pragma unroll
                for (int i = 0; i < 32; ++i) {
                    int kt = i >> 2, j = i & 3;
                    hv[i] = ld_a8(hb + kt * 16 + quad * 4 + j);
                }
#pragma unroll
                for (int i = 0; i < 32; ++i) ok &= ((u16)(hv[i] >> 48) == wantH);
                if (__all(ok)) break;
            }
#pragma unroll
            for (int kt = 0; kt < 8; ++kt) {
                half8 ah;
#pragma unroll
                for (int j = 0; j < 4; ++j) {
                    u64 v = hv[kt * 4 + j];
                    ah[2 * j]     = __builtin_bit_cast(f16, (u16)v);
                    ah[2 * j + 1] = __builtin_bit_cast(f16, (u16)(v >> 32));
                }
#pragma unroll
                for (int nt = 0; nt < 4; ++nt)
                    acc[nt] = __builtin_amdgcn_mfma_f32_16x16x32_f16(
                        ah, *(const half8*)&w1s[(((kt + 8) * 4 + nt) * 64 + l) * 8], acc[nt], 0, 0, 0);
            }
        }

        // ---- hid = tanh(acc + b1) -> tagged paired u64 stores (even lanes) ----
        {
            u64* hd = hid64 + (size_t)(t & 1) * 32768;
            const u64 tagw = (u64)(u16)(t + 1) << 48;
#pragma unroll
            for (int nt = 0; nt < 4; ++nt)
#pragma unroll
                for (int r = 0; r < 4; ++r) {
                    f16 v = (f16)fast_tanh(acc[nt][r] + b1v[nt]);
                    u32 pv = (u32)__builtin_bit_cast(u16, v);
                    u32 po = (u32)__shfl_xor((int)pv, 1);
                    if ((n15 & 1) == 0) {
                        int cp = ct * 32 + nt * 8 + (n15 >> 1);
                        st_a8(&hd[(size_t)(g * 64 + bo + r) * 128 + cp],
                              tagw | ((u64)po << 32) | pv);
                    }
                }
        }

        // ---- poll hid(tag t+1) + stage2: gates = sigmoid(hid @ W2 + b2) ----
        {
            f32x4 s2[4];
#pragma unroll
            for (int nt = 0; nt < 4; ++nt) s2[nt] = (f32x4){0.f, 0.f, 0.f, 0.f};
            const u64* hr = hid64 + (size_t)(t & 1) * 32768 + (size_t)(g * 64 + brow) * 128;
            const u16 wantM = (u16)(t + 1);
            u64 mv[32];
            for (;;) {
                bool ok = true;
#pragma unroll
                for (int i = 0; i < 32; ++i) {
                    int kt = i >> 2, j = i & 3;
                    mv[i] = ld_a8(hr + kt * 16 + quad * 4 + j);
                }
#pragma unroll
                for (int i = 0; i < 32; ++i) ok &= ((u16)(mv[i] >> 48) == wantM);
                if (__all(ok)) break;
            }
#pragma unroll
            for (int kt = 0; kt < 8; ++kt) {
                half8 ah;
#pragma unroll
                for (int j = 0; j < 4; ++j) {
                    u64 v = mv[kt * 4 + j];
                    ah[2 * j]     = __builtin_bit_cast(f16, (u16)v);
                    ah[2 * j + 1] = __builtin_bit_cast(f16, (u16)(v >> 32));
                }
#pragma unroll
                for (int nt = 0; nt < 4; ++nt)
                    s2[nt] = __builtin_amdgcn_mfma_f32_16x16x32_f16(
                        ah, *(const half8*)&w2s[((kt * 4 + nt) * 64 + l) * 8], s2[nt], 0, 0, 0);
            }
            // epilogue: sigmoid (u-gate: tanh(sigmoid) pre-applied) -> u16 fixed, tagged pairs
            u64* gd = gat64 + (size_t)(t & 1) * 32768;
            const u64 tagw = (u64)(u16)(t + 1) << 48;
#pragma unroll
            for (int nt = 0; nt < 4; ++nt)
#pragma unroll
                for (int r = 0; r < 4; ++r) {
                    float sg = fast_sig(s2[nt][r] + b2v[nt]);
                    if (g == 2) sg = fast_tanh(sg);
                    u32 q  = (u32)(sg * 65535.0f + 0.5f);
                    u32 oq = (u32)__shfl_xor((int)q, 1);
                    if ((n15 & 1) == 0) {
                        int cp = ct * 32 + nt * 8 + (n15 >> 1);
                        st_a8(&gd[(size_t)(g * 64 + bo + r) * 128 + cp],
                              tagw | ((u64)oq << 16) | q);
                    }
                }
        }

        // ---- update: poll own 4 gates (8 tagged u64), c in registers ----
        {
            const u64* gb = gat64 + (size_t)(t & 1) * 32768 + (size_t)urow * 128 + (ucol >> 1);
            const u16 wantG = (u16)(t + 1);
            u64 gv[8];
            for (;;) {
                bool ok = true;
#pragma unroll
                for (int gg = 0; gg < 4; ++gg) {
                    gv[gg * 2]     = ld_a8(gb + gg * 8192);
                    gv[gg * 2 + 1] = ld_a8(gb + gg * 8192 + 1);
                }
#pragma unroll
                for (int i = 0; i < 8; ++i) ok &= ((u16)(gv[i] >> 48) == wantG);
                if (__all(ok)) break;
            }
            float4 ov;
            const float s = 1.0f / 65535.0f;
            u64* hw = h64 + (size_t)((t + 1) & 1) * 8192;
            const u64 tagH = (u64)(u16)(t + 1) << 48;
            u64 hp[2];
#pragma unroll
            for (int k = 0; k < 4; ++k) {
                int wsel = k >> 1, sh = 16 * (k & 1);
                float f  = (float)((gv[0 + wsel] >> sh) & 0xffff) * s;
                float i  = (float)((gv[2 + wsel] >> sh) & 0xffff) * s;
                float gu = (float)((gv[4 + wsel] >> sh) & 0xffff) * s;  // tanh pre-applied
                float o  = (float)((gv[6 + wsel] >> sh) & 0xffff) * s;
                creg[k] = f * creg[k] + i * gu;
                float hn = o * fast_tanh(creg[k]);
                ((float*)&ov)[k] = hn;
                u64 hb16 = (u64)__builtin_bit_cast(u16, (f16)hn);
                if ((k & 1) == 0) hp[k >> 1] = tagH | hb16;
                else              hp[k >> 1] |= (hb16 << 32);
            }
            *(float4*)(out + (size_t)t * NELEM + e0) = ov;
            st_a8(&hw[urow * 128 + (ucol >> 1)],     hp[0]);
            st_a8(&hw[urow * 128 + (ucol >> 1) + 1], hp[1]);
            if (t == TS - 1) {
                *(float4*)(out + (size_t)TS * NELEM + e0) = ov;             // hx
                float4 cv = {creg[0], creg[1], creg[2], creg[3]};
                *(float4*)(out + (size_t)TS * NELEM + NELEM + e0) = cv;     // cx
            }
        }

        // ---- stage1 x-part for t+1 (overlaps the h-exchange latency) ----
#pragma unroll
        for (int nt = 0; nt < 4; ++nt) acc[nt] = (f32x4){0.f, 0.f, 0.f, 0.f};
        if (t < TS - 1) {
            const float* xr = x + ((size_t)(t + 1) * 64 + brow) * 256;
#pragma unroll
            for (int kt = 0; kt < 8; ++kt) {
                float a[8];
                *(float4*)&a[0] = *(const float4*)(xr + kt * 32 + quad * 8);
                *(float4*)&a[4] = *(const float4*)(xr + kt * 32 + quad * 8 + 4);
                half8 ah;
#pragma unroll
                for (int j = 0; j < 8; ++j) ah[j] = (f16)a[j];
#pragma unroll
                for (int nt = 0; nt < 4; ++nt)
                    acc[nt] = __builtin_amdgcn_mfma_f32_16x16x32_f16(
                        ah, *(const half8*)&w1s[((kt * 4 + nt) * 64 + l) * 8], acc[nt], 0, 0, 0);
            }
        }
    }
}

extern "C" void kernel_launch(void* const* d_in, const int* in_sizes, int n_in,
                              void* d_out, int out_size, void* d_ws, size_t ws_size,
                              hipStream_t stream)
{
    const float* x  = (const float*)d_in[0];
    const float* W1 = (const float*)d_in[1];
    const float* b1 = (const float*)d_in[2];
    const float* W2 = (const float*)d_in[3];
    const float* b2 = (const float*)d_in[4];
    float* out = (float*)d_out;

    char* ws = (char*)d_ws;
    u64* h64   = (u64*)ws;                           // 128 KB: [2][64][128]
    u64* hid64 = (u64*)(ws + 131072);                // 512 KB: [2][4][64][128]
    u64* gat64 = (u64*)(ws + 131072 + 524288);       // 512 KB: [2][4][64][128]
    // total exchange region: 1179648 B = 147456 u64

    qinit<<<64, 256, 0, stream>>>((u64*)ws, 147456);
    qlstm_persist<<<16, 256, 0, stream>>>(x, W1, b1, W2, b2, out,
                                          h64, hid64, gat64);
}

// Round 2
// 14551.727 us; speedup vs baseline: 1.6472x; 1.6472x over previous
//
#include <hip/hip_runtime.h>
#include <math.h>

// HybridQLSTM persistent kernel v5: 2 barrier rounds/step (was 3).
// T=1024, B=64, D_IN=256, H=256, 4 gates.
//
// Decomposition change vs v3: 16 blocks = 16 column tiles of 16 cols, each
// block owns ALL 4 gates for its columns (same 96 KB LDS: W1 4x512x16 +
// W2 4x256x16 f16). Consequence: after stage2 a block holds f,i,u,o for its
// own (row, col) elements in registers -> gate exchange + its barrier deleted,
// update runs in-register unquantized. Exchanges/step: hid (128 KB), h (32 KB).
// All exchange stores packed to u64 (4 x f16) via 4-lane register transpose:
// 5 wide sc1 stores/lane/step vs v3's 33 narrow ones.
// Barrier: v3's proven all-poll flag barrier, 2 epochs/step.

#define TS    1024
#define NELEM 16384

typedef unsigned long long u64;
typedef unsigned int u32;
typedef unsigned short u16;
typedef _Float16 f16;
typedef __attribute__((ext_vector_type(8))) _Float16 half8;
typedef __attribute__((ext_vector_type(8))) unsigned short ushort8;
typedef __attribute__((ext_vector_type(4))) float f32x4;

// ---- relaxed agent-scope (IC-coherent) accessors ----
__device__ __forceinline__ u64 ld_a8(const u64* p) {
    return __hip_atomic_load(p, __ATOMIC_RELAXED, __HIP_MEMORY_SCOPE_AGENT);
}
__device__ __forceinline__ void st_a8(u64* p, u64 v) {
    __hip_atomic_store(p, v, __ATOMIC_RELAXED, __HIP_MEMORY_SCOPE_AGENT);
}

// fast tanh/sigmoid via v_exp/v_rcp (err ~1e-6, << f16 quantization)
__device__ __forceinline__ float fast_tanh(float xx) {
    float e = __expf(2.0f * xx);
    return 1.0f - 2.0f * __builtin_amdgcn_rcpf(e + 1.0f);
}
__device__ __forceinline__ float fast_sig(float xx) {
    return __builtin_amdgcn_rcpf(1.0f + __expf(-xx));
}

// ---- symmetric all-poll barrier over 16 blocks (v3 mechanism, unchanged) ----
__device__ __forceinline__ void gbar(int e, int bid, int tid, int* flags) {
    __syncthreads();
    if (tid == 0)
        __hip_atomic_store(&flags[bid * 16], e, __ATOMIC_RELAXED, __HIP_MEMORY_SCOPE_AGENT);
    const int l = tid & 63;
    for (;;) {
        int ok = 1;
        if (l < 16) {
            int v = __hip_atomic_load(&flags[l * 16], __ATOMIC_RELAXED, __HIP_MEMORY_SCOPE_AGENT);
            ok = (v >= e);
        }
        if (__all(ok)) break;
        __builtin_amdgcn_s_sleep(1);
    }
    asm volatile("" ::: "memory");
}

__device__ __forceinline__ half8 h8_from(u64 v0, u64 v1) {
    ushort8 t;
#pragma unroll
    for (int q = 0; q < 4; ++q) {
        t[q]     = (u16)(v0 >> (16 * q));
        t[4 + q] = (u16)(v1 >> (16 * q));
    }
    return __builtin_bit_cast(half8, t);
}

// 4x4 transpose across 4 consecutive lanes (p = lane&3).
// In: v[r] = (row r, col p). Out: v[r] = (row p, col r).
__device__ __forceinline__ void xpose4(float v[4], int p) {
#pragma unroll
    for (int m = 1; m <= 2; m <<= 1) {
        float nv[4];
#pragma unroll
        for (int r = 0; r < 4; ++r) {
            float ex = __shfl_xor(v[r ^ m], m);
            nv[r] = ((r ^ p) & m) ? ex : v[r];
        }
#pragma unroll
        for (int r = 0; r < 4; ++r) v[r] = nv[r];
    }
}

__device__ __forceinline__ u64 pk4f16(const float v[4]) {
    u64 r = 0;
#pragma unroll
    for (int k = 0; k < 4; ++k)
        r |= (u64)__builtin_bit_cast(u16, (f16)v[k]) << (16 * k);
    return r;
}

// ---- init: zero h (f16) and flags; reruns every launch/replay ----
__global__ __launch_bounds__(256) void qinit(u64* h64, int* flags) {
    int i = blockIdx.x * 256 + threadIdx.x;   // 16 blocks -> 4096
    st_a8(&h64[i], 0ull);                     // 4096 u64 = 32 KB f16 zeros
    if (i < 128)
        st_a8((u64*)flags + i, 0ull);         // 256 ints
}

// ---- persistent kernel ----
__global__ __launch_bounds__(256, 1) void qlstm_persist(
    const float* __restrict__ x,      // [TS, 64, 256] fp32
    const float* __restrict__ W1,     // [4, 512, 256]
    const float* __restrict__ b1,     // [4, 256]
    const float* __restrict__ W2,     // [4, 256, 256]
    const float* __restrict__ b2,     // [4, 256]
    float* __restrict__ out,          // stacked ++ hx ++ cx
    u64* __restrict__ h64,            // [64][64]  h f16, u64-packed (4 cols)
    u64* __restrict__ hid64,          // [4][64][64] hid f16, u64-packed
    int* __restrict__ flags)          // 16 flags, 64 B apart
{
    const int tid = threadIdx.x;
    const int bid = blockIdx.x;
    const int ct = bid;               // column tile 0..15 (16 cols, all gates)

    // LDS: W1 [16 kt][4 g][64 lanes][8 f16] = 64 KB ; W2 [8 kt][4 g][...] = 32 KB
    __shared__ f16 w1s[16 * 4 * 512];
    __shared__ f16 w2s[8 * 4 * 512];
    {
        for (int i = tid; i < 16 * 4 * 64; i += 256) {
            int kt = i >> 8, g = (i >> 6) & 3, lane = i & 63;
            int k0 = kt * 32 + (lane >> 4) * 8;
            int col = ct * 16 + (lane & 15);
            const float* W1g = W1 + (size_t)g * 512 * 256;
#pragma unroll
            for (int j = 0; j < 8; ++j)
                w1s[(size_t)i * 8 + j] = (f16)W1g[(size_t)(k0 + j) * 256 + col];
        }
        for (int i = tid; i < 8 * 4 * 64; i += 256) {
            int kt = i >> 8, g = (i >> 6) & 3, lane = i & 63;
            int k0 = kt * 32 + (lane >> 4) * 8;
            int col = ct * 16 + (lane & 15);
            const float* W2g = W2 + (size_t)g * 256 * 256;
#pragma unroll
            for (int j = 0; j < 8; ++j)
                w2s[(size_t)i * 8 + j] = (f16)W2g[(size_t)(k0 + j) * 256 + col];
        }
        __syncthreads();
    }

    const int l    = tid & 63;
    const int w    = tid >> 6;        // wave: owns batch rows w*16 .. w*16+15
    const int quad = l >> 4;
    const int n15  = l & 15;
    const int brow = w * 16 + n15;    // A-operand row this lane loads
    const int bo   = w * 16 + quad * 4;  // C/D row base
    const int p    = l & 3;           // lane-in-quad for 4x4 transposes
    const int cq   = ct * 4 + (n15 >> 2);          // u64 col index within row
    const int cbase = ct * 16 + (n15 & ~3);        // f32 col base after xpose
    float b1v[4], b2v[4];
#pragma unroll
    for (int g = 0; g < 4; ++g) {
        b1v[g] = b1[g * 256 + ct * 16 + n15];
        b2v[g] = b2[g * 256 + ct * 16 + n15];
    }
    float creg[4] = {0.f, 0.f, 0.f, 0.f};

    f32x4 acc[4];
#pragma unroll
    for (int g = 0; g < 4; ++g) acc[g] = (f32x4){0.f, 0.f, 0.f, 0.f};

    // ---- stage1 x-part (kt 0..7), no h dependence; peeled for t=0 ----
    {
        const float* xr = x + (size_t)brow * 256;
#pragma unroll
        for (int kt = 0; kt < 8; ++kt) {
            float a[8];
            *(float4*)&a[0] = *(const float4*)(xr + kt * 32 + quad * 8);
            *(float4*)&a[4] = *(const float4*)(xr + kt * 32 + quad * 8 + 4);
            half8 ah;
#pragma unroll
            for (int j = 0; j < 8; ++j) ah[j] = (f16)a[j];
#pragma unroll
            for (int g = 0; g < 4; ++g)
                acc[g] = __builtin_amdgcn_mfma_f32_16x16x32_f16(
                    ah, *(const half8*)&w1s[((kt * 4 + g) * 64 + l) * 8], acc[g], 0, 0, 0);
        }
    }

    for (int t = 0; t < TS; ++t) {
        // ---- stage1 h-part (kt 8..15): A = h f16 from IC; load all, then MFMA ----
        {
            const u64* hp = h64 + (size_t)brow * 64;
            u64 hv[16];
#pragma unroll
            for (int kt = 0; kt < 8; ++kt) {
                int ko = kt * 8 + quad * 2;
                hv[kt * 2]     = ld_a8(hp + ko);
                hv[kt * 2 + 1] = ld_a8(hp + ko + 1);
            }
#pragma unroll
            for (int kt = 0; kt < 8; ++kt) {
                half8 ah = h8_from(hv[kt * 2], hv[kt * 2 + 1]);
#pragma unroll
                for (int g = 0; g < 4; ++g)
                    acc[g] = __builtin_amdgcn_mfma_f32_16x16x32_f16(
                        ah, *(const half8*)&w1s[(((kt + 8) * 4 + g) * 64 + l) * 8], acc[g], 0, 0, 0);
            }
        }

        // ---- hid = tanh(acc + b1): transpose to row-contiguous, 1 u64 store/g ----
#pragma unroll
        for (int g = 0; g < 4; ++g) {
            float mv[4];
#pragma unroll
            for (int r = 0; r < 4; ++r) mv[r] = fast_tanh(acc[g][r] + b1v[g]);
            xpose4(mv, p);   // lane now holds row bo+p, cols cbase..cbase+3
            st_a8(&hid64[(size_t)(g * 64 + bo + p) * 64 + cq], pk4f16(mv));
        }

        gbar(2 * t + 1, bid, tid, flags);       // hid(t) visible

        // ---- stage2: s2[g] = hid[g] @ W2[g]; A differs per gate ----
        f32x4 s2[4];
#pragma unroll
        for (int g = 0; g < 4; ++g) s2[g] = (f32x4){0.f, 0.f, 0.f, 0.f};
        {
            u64 mv[64];
#pragma unroll
            for (int kt = 0; kt < 8; ++kt)
#pragma unroll
                for (int g = 0; g < 4; ++g) {
                    const u64* hr = hid64 + (size_t)(g * 64 + brow) * 64 + kt * 8 + quad * 2;
                    mv[(kt * 4 + g) * 2]     = ld_a8(hr);
                    mv[(kt * 4 + g) * 2 + 1] = ld_a8(hr + 1);
                }
#pragma unroll
            for (int kt = 0; kt < 8; ++kt)
#pragma unroll
                for (int g = 0; g < 4; ++g) {
                    half8 ah = h8_from(mv[(kt * 4 + g) * 2], mv[(kt * 4 + g) * 2 + 1]);
                    s2[g] = __builtin_amdgcn_mfma_f32_16x16x32_f16(
                        ah, *(const half8*)&w2s[((kt * 4 + g) * 64 + l) * 8], s2[g], 0, 0, 0);
                }
        }

        // ---- update fully in-register: f,i,u,o are s2[0..3] at same (row,col) ----
        {
            float hn[4];
#pragma unroll
            for (int r = 0; r < 4; ++r) {
                float f  = fast_sig(s2[0][r] + b2v[0]);
                float ig = fast_sig(s2[1][r] + b2v[1]);
                float ug = fast_tanh(fast_sig(s2[2][r] + b2v[2]));
                float og = fast_sig(s2[3][r] + b2v[3]);
                creg[r] = f * creg[r] + ig * ug;
                hn[r] = og * fast_tanh(creg[r]);
            }
            xpose4(hn, p);   // lane: row bo+p, cols cbase..cbase+3
            float4 ov = {hn[0], hn[1], hn[2], hn[3]};
            *(float4*)(out + (size_t)t * NELEM + (size_t)(bo + p) * 256 + cbase) = ov;
            st_a8(&h64[(size_t)(bo + p) * 64 + cq], pk4f16(hn));
            if (t == TS - 1) {
                *(float4*)(out + (size_t)TS * NELEM + (size_t)(bo + p) * 256 + cbase) = ov;  // hx
                float cv[4] = {creg[0], creg[1], creg[2], creg[3]};
                xpose4(cv, p);
                float4 cvv = {cv[0], cv[1], cv[2], cv[3]};
                *(float4*)(out + (size_t)TS * NELEM + NELEM + (size_t)(bo + p) * 256 + cbase) = cvv;  // cx
            }
        }

        // ---- stage1 x-part for t+1 (overlaps barrier stragglers) ----
#pragma unroll
        for (int g = 0; g < 4; ++g) acc[g] = (f32x4){0.f, 0.f, 0.f, 0.f};
        if (t < TS - 1) {
            const float* xr = x + ((size_t)(t + 1) * 64 + brow) * 256;
#pragma unroll
            for (int kt = 0; kt < 8; ++kt) {
                float a[8];
                *(float4*)&a[0] = *(const float4*)(xr + kt * 32 + quad * 8);
                *(float4*)&a[4] = *(const float4*)(xr + kt * 32 + quad * 8 + 4);
                half8 ah;
#pragma unroll
                for (int j = 0; j < 8; ++j) ah[j] = (f16)a[j];
#pragma unroll
                for (int g = 0; g < 4; ++g)
                    acc[g] = __builtin_amdgcn_mfma_f32_16x16x32_f16(
                        ah, *(const half8*)&w1s[((kt * 4 + g) * 64 + l) * 8], acc[g], 0, 0, 0);
            }
        }

        gbar(2 * t + 2, bid, tid, flags);       // h(t+1) visible for next step
    }
}

extern "C" void kernel_launch(void* const* d_in, const int* in_sizes, int n_in,
                              void* d_out, int out_size, void* d_ws, size_t ws_size,
                              hipStream_t stream)
{
    const float* x  = (const float*)d_in[0];
    const float* W1 = (const float*)d_in[1];
    const float* b1 = (const float*)d_in[2];
    const float* W2 = (const float*)d_in[3];
    const float* b2 = (const float*)d_in[4];
    float* out = (float*)d_out;

    char* ws = (char*)d_ws;
    u64* h64   = (u64*)ws;                      // 32 KB : [64][64] u64
    u64* hid64 = (u64*)(ws + 32768);            // 128 KB: [4][64][64] u64
    int* flags = (int*)(ws + 32768 + 131072);   // 1 KB

    qinit<<<16, 256, 0, stream>>>(h64, flags);
    qlstm_persist<<<16, 256, 0, stream>>>(x, W1, b1, W2, b2, out,
                                          h64, hid64, flags);
}

// Round 3
// 12614.677 us; speedup vs baseline: 1.9001x; 1.1536x over previous
//
#include <hip/hip_runtime.h>
#include <math.h>

// HybridQLSTM persistent kernel v6: v3's light-traffic decomposition
// (4 gates x 4 col-tiles, 3 light barrier rounds/step, 288 B/lane/step sc1
// loads) + poll-storm fix + packed exchange stores + fast activations.
// T=1024, B=64, D_IN=256, H=256.
//
// Changes vs v3 (13.4 ms):
//  - flags: 16 ints in ONE 64B line; only wave 0 polls (1 coalesced load/iter)
//    -> ~64x fewer poll transactions on the coherent path.
//  - hid/gates/h stores packed to u64 (4 x 16-bit) via 4-lane register
//    transpose (v5-proven): 9 wide sc1 stores/lane/step vs v3's 33 narrow.
//  - fast_tanh/fast_sig via v_exp/v_rcp (v5-proven, err ~1e-6 << f16 quant).
//  - gates stay u16 fixed-point (v3-proven accuracy through the c recurrence).

#define TS    1024
#define NELEM 16384

typedef unsigned long long u64;
typedef unsigned int u32;
typedef unsigned short u16;
typedef _Float16 f16;
typedef __attribute__((ext_vector_type(8))) _Float16 half8;
typedef __attribute__((ext_vector_type(8))) unsigned short ushort8;
typedef __attribute__((ext_vector_type(4))) float f32x4;

// ---- relaxed agent-scope (coherent-path) accessors ----
__device__ __forceinline__ u64 ld_a8(const u64* p) {
    return __hip_atomic_load(p, __ATOMIC_RELAXED, __HIP_MEMORY_SCOPE_AGENT);
}
__device__ __forceinline__ void st_a8(u64* p, u64 v) {
    __hip_atomic_store(p, v, __ATOMIC_RELAXED, __HIP_MEMORY_SCOPE_AGENT);
}

// fast tanh/sigmoid via v_exp/v_rcp (err ~1e-6, << 16-bit quantization)
__device__ __forceinline__ float fast_tanh(float xx) {
    float e = __expf(2.0f * xx);
    return 1.0f - 2.0f * __builtin_amdgcn_rcpf(e + 1.0f);
}
__device__ __forceinline__ float fast_sig(float xx) {
    return __builtin_amdgcn_rcpf(1.0f + __expf(-xx));
}

// ---- barrier over 16 blocks: one flag line, wave-0-only poll ----
// Leading __syncthreads drains each wave's sc1 data stores before the flag
// store; trailing __syncthreads releases waves 1..3 after wave 0's poll.
__device__ __forceinline__ void gbar(int e, int bid, int tid, int* flags) {
    __syncthreads();
    if (tid == 0)
        __hip_atomic_store(&flags[bid], e, __ATOMIC_RELAXED, __HIP_MEMORY_SCOPE_AGENT);
    if (tid < 64) {
        for (;;) {
            int ok = 1;
            if (tid < 16) {
                int v = __hip_atomic_load(&flags[tid], __ATOMIC_RELAXED, __HIP_MEMORY_SCOPE_AGENT);
                ok = (v >= e);
            }
            if (__all(ok)) break;
            __builtin_amdgcn_s_sleep(1);
        }
    }
    __syncthreads();
    asm volatile("" ::: "memory");
}

__device__ __forceinline__ half8 h8_from(u64 v0, u64 v1) {
    ushort8 t;
#pragma unroll
    for (int q = 0; q < 4; ++q) {
        t[q]     = (u16)(v0 >> (16 * q));
        t[4 + q] = (u16)(v1 >> (16 * q));
    }
    return __builtin_bit_cast(half8, t);
}

// 4x4 transpose across 4 consecutive lanes (p = lane&3).
// In: v[r] = (row r, col p). Out: v[r] = (row p, col r).
__device__ __forceinline__ void xpose4(float v[4], int p) {
#pragma unroll
    for (int m = 1; m <= 2; m <<= 1) {
        float nv[4];
#pragma unroll
        for (int r = 0; r < 4; ++r) {
            float ex = __shfl_xor(v[r ^ m], m);
            nv[r] = ((r ^ p) & m) ? ex : v[r];
        }
#pragma unroll
        for (int r = 0; r < 4; ++r) v[r] = nv[r];
    }
}

__device__ __forceinline__ u64 pk4f16(const float v[4]) {
    u64 r = 0;
#pragma unroll
    for (int k = 0; k < 4; ++k)
        r |= (u64)__builtin_bit_cast(u16, (f16)v[k]) << (16 * k);
    return r;
}

__device__ __forceinline__ u64 pk4q16(const float v[4]) {
    u64 r = 0;
#pragma unroll
    for (int k = 0; k < 4; ++k)
        r |= (u64)(u16)(v[k] * 65535.0f + 0.5f) << (16 * k);
    return r;
}

// ---- init: zero h (f16) and flags; reruns every launch/replay ----
__global__ __launch_bounds__(256) void qinit(u64* h64, int* flags) {
    int i = blockIdx.x * 256 + threadIdx.x;   // 16 blocks -> 4096
    st_a8(&h64[i], 0ull);                     // 4096 u64 = 32 KB f16 zeros
    if (i < 16)
        __hip_atomic_store(&flags[i], 0, __ATOMIC_RELAXED, __HIP_MEMORY_SCOPE_AGENT);
}

// ---- persistent kernel ----
__global__ __launch_bounds__(256, 1) void qlstm_persist(
    const float* __restrict__ x,      // [TS, 64, 256] fp32
    const float* __restrict__ W1,     // [4, 512, 256]
    const float* __restrict__ b1,     // [4, 256]
    const float* __restrict__ W2,     // [4, 256, 256]
    const float* __restrict__ b2,     // [4, 256]
    float* __restrict__ out,          // stacked ++ hx ++ cx
    u64* __restrict__ h64,            // [64][64]   h f16, u64-packed (4 cols)
    u64* __restrict__ hid64,          // [4][64][64] hid f16, u64-packed
    u64* __restrict__ gat64,          // [4][64][64] gates u16-fixed, packed
    int* __restrict__ flags)          // 16 ints, one 64B line
{
    const int tid = threadIdx.x;
    const int bid = blockIdx.x;
    const int g  = bid >> 2;          // gate 0..3
    const int ct = bid & 3;           // column tile 0..3 (64 cols)

    // LDS: W1 [16 kt][4 nt][64 lanes][8 f16] = 64 KB ; W2 [8 kt][4 nt][...] = 32 KB
    __shared__ f16 w1s[16 * 4 * 512];
    __shared__ f16 w2s[8 * 4 * 512];
    {
        const float* W1g = W1 + (size_t)g * 512 * 256;
        for (int i = tid; i < 16 * 4 * 64; i += 256) {
            int kt = i >> 8, nt = (i >> 6) & 3, lane = i & 63;
            int k0 = kt * 32 + (lane >> 4) * 8;
            int col = ct * 64 + nt * 16 + (lane & 15);
#pragma unroll
            for (int j = 0; j < 8; ++j)
                w1s[(size_t)i * 8 + j] = (f16)W1g[(size_t)(k0 + j) * 256 + col];
        }
        const float* W2g = W2 + (size_t)g * 256 * 256;
        for (int i = tid; i < 8 * 4 * 64; i += 256) {
            int kt = i >> 8, nt = (i >> 6) & 3, lane = i & 63;
            int k0 = kt * 32 + (lane >> 4) * 8;
            int col = ct * 64 + nt * 16 + (lane & 15);
#pragma unroll
            for (int j = 0; j < 8; ++j)
                w2s[(size_t)i * 8 + j] = (f16)W2g[(size_t)(k0 + j) * 256 + col];
        }
        __syncthreads();
    }

    const int l    = tid & 63;
    const int w    = tid >> 6;        // wave: owns batch rows w*16 .. w*16+15
    const int quad = l >> 4;
    const int n15  = l & 15;
    const int brow = w * 16 + n15;    // A-operand row this lane loads
    const int bo   = w * 16 + quad * 4;  // C/D row base
    const int p    = l & 3;           // lane-in-quad for 4x4 transposes
    const int cqb  = ct * 16 + (n15 >> 2);  // packed u64-col base (+ nt*4)
    float b1v[4], b2v[4];
#pragma unroll
    for (int nt = 0; nt < 4; ++nt) {
        b1v[nt] = b1[g * 256 + ct * 64 + nt * 16 + n15];
        b2v[nt] = b2[g * 256 + ct * 64 + nt * 16 + n15];
    }
    // update-phase ownership: 4 consecutive cols of one row
    const int e0   = bid * 1024 + tid * 4;       // [0, 16384)
    const int urow = e0 >> 8;
    const int ucq  = (e0 & 255) >> 2;            // u64 col index
    float creg[4] = {0.f, 0.f, 0.f, 0.f};

    f32x4 acc[4];
#pragma unroll
    for (int nt = 0; nt < 4; ++nt) acc[nt] = (f32x4){0.f, 0.f, 0.f, 0.f};

    // ---- stage1 x-part (kt 0..7), no h dependence; peeled for t=0 ----
    {
        const float* xr = x + (size_t)brow * 256;
#pragma unroll
        for (int kt = 0; kt < 8; ++kt) {
            float a[8];
            *(float4*)&a[0] = *(const float4*)(xr + kt * 32 + quad * 8);
            *(float4*)&a[4] = *(const float4*)(xr + kt * 32 + quad * 8 + 4);
            half8 ah;
#pragma unroll
            for (int j = 0; j < 8; ++j) ah[j] = (f16)a[j];
#pragma unroll
            for (int nt = 0; nt < 4; ++nt)
                acc[nt] = __builtin_amdgcn_mfma_f32_16x16x32_f16(
                    ah, *(const half8*)&w1s[((kt * 4 + nt) * 64 + l) * 8], acc[nt], 0, 0, 0);
        }
    }

    for (int t = 0; t < TS; ++t) {
        // ---- stage1 h-part (kt 8..15): A = h f16 from exchange buffer ----
        {
            const u64* hp = h64 + (size_t)brow * 64;
            u64 hv[16];
#pragma unroll
            for (int kt = 0; kt < 8; ++kt) {
                int ko = kt * 8 + quad * 2;
                hv[kt * 2]     = ld_a8(hp + ko);
                hv[kt * 2 + 1] = ld_a8(hp + ko + 1);
            }
#pragma unroll
            for (int kt = 0; kt < 8; ++kt) {
                half8 ah = h8_from(hv[kt * 2], hv[kt * 2 + 1]);
#pragma unroll
                for (int nt = 0; nt < 4; ++nt)
                    acc[nt] = __builtin_amdgcn_mfma_f32_16x16x32_f16(
                        ah, *(const half8*)&w1s[(((kt + 8) * 4 + nt) * 64 + l) * 8], acc[nt], 0, 0, 0);
            }
        }

        // ---- hid = tanh(acc + b1): transpose, 1 packed u64 store per nt ----
#pragma unroll
        for (int nt = 0; nt < 4; ++nt) {
            float mv[4];
#pragma unroll
            for (int r = 0; r < 4; ++r) mv[r] = fast_tanh(acc[nt][r] + b1v[nt]);
            xpose4(mv, p);   // lane now holds row bo+p, 4 consecutive cols
            st_a8(&hid64[(size_t)(g * 64 + bo + p) * 64 + cqb + nt * 4], pk4f16(mv));
        }

        gbar(3 * t + 1, bid, tid, flags);       // hid(t) visible

        // ---- stage2: gates = sigmoid(hid @ W2 + b2) -> packed u16 fixed ----
        {
            f32x4 s2[4];
#pragma unroll
            for (int nt = 0; nt < 4; ++nt) s2[nt] = (f32x4){0.f, 0.f, 0.f, 0.f};
            const u64* hr = hid64 + (size_t)(g * 64 + brow) * 64;
            u64 mv2[16];
#pragma unroll
            for (int kt = 0; kt < 8; ++kt) {
                int ko = kt * 8 + quad * 2;
                mv2[kt * 2]     = ld_a8(hr + ko);
                mv2[kt * 2 + 1] = ld_a8(hr + ko + 1);
            }
#pragma unroll
            for (int kt = 0; kt < 8; ++kt) {
                half8 ah = h8_from(mv2[kt * 2], mv2[kt * 2 + 1]);
#pragma unroll
                for (int nt = 0; nt < 4; ++nt)
                    s2[nt] = __builtin_amdgcn_mfma_f32_16x16x32_f16(
                        ah, *(const half8*)&w2s[((kt * 4 + nt) * 64 + l) * 8], s2[nt], 0, 0, 0);
            }
#pragma unroll
            for (int nt = 0; nt < 4; ++nt) {
                float gv[4];
#pragma unroll
                for (int r = 0; r < 4; ++r) {
                    float sg = fast_sig(s2[nt][r] + b2v[nt]);
                    if (g == 2) sg = fast_tanh(sg);   // u-gate: pre-apply tanh
                    gv[r] = sg;
                }
                xpose4(gv, p);
                st_a8(&gat64[(size_t)(g * 64 + bo + p) * 64 + cqb + nt * 4], pk4q16(gv));
            }
        }

        gbar(3 * t + 2, bid, tid, flags);       // gates(t) visible

        // ---- update: 4 elems/thread, c in registers ----
        {
            u64 qf = ld_a8(&gat64[(size_t)(0 * 64 + urow) * 64 + ucq]);
            u64 qi = ld_a8(&gat64[(size_t)(1 * 64 + urow) * 64 + ucq]);
            u64 qu = ld_a8(&gat64[(size_t)(2 * 64 + urow) * 64 + ucq]);
            u64 qo = ld_a8(&gat64[(size_t)(3 * 64 + urow) * 64 + ucq]);
            float4 ov;
            u64 hpack = 0;
            const float s = 1.0f / 65535.0f;
#pragma unroll
            for (int k = 0; k < 4; ++k) {
                float f  = (float)((qf >> (16 * k)) & 0xffff) * s;
                float ig = (float)((qi >> (16 * k)) & 0xffff) * s;
                float ug = (float)((qu >> (16 * k)) & 0xffff) * s;  // tanh pre-applied
                float og = (float)((qo >> (16 * k)) & 0xffff) * s;
                creg[k] = f * creg[k] + ig * ug;
                float hn = og * fast_tanh(creg[k]);
                ((float*)&ov)[k] = hn;
                hpack |= (u64)__builtin_bit_cast(u16, (f16)hn) << (16 * k);
            }
            *(float4*)(out + (size_t)t * NELEM + e0) = ov;
            st_a8(&h64[(size_t)urow * 64 + ucq], hpack);
            if (t == TS - 1) {
                *(float4*)(out + (size_t)TS * NELEM + e0) = ov;             // hx
                float4 cv = {creg[0], creg[1], creg[2], creg[3]};
                *(float4*)(out + (size_t)TS * NELEM + NELEM + e0) = cv;     // cx
            }
        }

        // ---- stage1 x-part for t+1 (overlaps barrier stragglers) ----
#pragma unroll
        for (int nt = 0; nt < 4; ++nt) acc[nt] = (f32x4){0.f, 0.f, 0.f, 0.f};
        if (t < TS - 1) {
            const float* xr = x + ((size_t)(t + 1) * 64 + brow) * 256;
#pragma unroll
            for (int kt = 0; kt < 8; ++kt) {
                float a[8];
                *(float4*)&a[0] = *(const float4*)(xr + kt * 32 + quad * 8);
                *(float4*)&a[4] = *(const float4*)(xr + kt * 32 + quad * 8 + 4);
                half8 ah;
#pragma unroll
                for (int j = 0; j < 8; ++j) ah[j] = (f16)a[j];
#pragma unroll
                for (int nt = 0; nt < 4; ++nt)
                    acc[nt] = __builtin_amdgcn_mfma_f32_16x16x32_f16(
                        ah, *(const half8*)&w1s[((kt * 4 + nt) * 64 + l) * 8], acc[nt], 0, 0, 0);
            }
        }

        gbar(3 * t + 3, bid, tid, flags);       // h(t+1) visible for next step
    }
}

extern "C" void kernel_launch(void* const* d_in, const int* in_sizes, int n_in,
                              void* d_out, int out_size, void* d_ws, size_t ws_size,
                              hipStream_t stream)
{
    const float* x  = (const float*)d_in[0];
    const float* W1 = (const float*)d_in[1];
    const float* b1 = (const float*)d_in[2];
    const float* W2 = (const float*)d_in[3];
    const float* b2 = (const float*)d_in[4];
    float* out = (float*)d_out;

    char* ws = (char*)d_ws;
    u64* h64   = (u64*)ws;                      // 32 KB : [64][64] u64
    u64* hid64 = (u64*)(ws + 32768);            // 128 KB: [4][64][64] u64
    u64* gat64 = (u64*)(ws + 32768 + 131072);   // 128 KB: [4][64][64] u64
    int* flags = (int*)(ws + 32768 + 131072 + 131072);  // 64 B, one line

    qinit<<<16, 256, 0, stream>>>(h64, flags);
    qlstm_persist<<<16, 256, 0, stream>>>(x, W1, b1, W2, b2, out,
                                          h64, hid64, gat64, flags);
}